// Round 7
// baseline (207.525 us; speedup 1.0000x reference)
//
#include <hip/hip_runtime.h>

// (B,C,L,H,W) = (4,64,16,32,32), K=1024, D=C=64
constexpr int Cc   = 64;
constexpr int Kc   = 1024;
constexpr int Dc   = 64;
constexpr int LHWc = 16 * 32 * 32;        // 16384
constexpr int Nc   = 4 * LHWc;            // 65536 vectors
constexpr int QSIZE    = 4 * Cc * LHWc;   // 4194304
constexpr int OFF_LOSS = QSIZE;           // 4194304
constexpr int OFF_IDX  = QSIZE + 1;       // 4194305

constexpr int BLK_ROWS = 128;             // rows per block
constexpr int WAVES    = 16;              // 1024 threads

typedef __attribute__((ext_vector_type(8))) short short8;   // 8 x bf16 bits
typedef __attribute__((ext_vector_type(4))) float f32x4;

static __device__ __forceinline__ unsigned short f2bf(float f) {
    unsigned u = __float_as_uint(f);
    u += 0x7FFFu + ((u >> 16) & 1u);      // RNE (finite data only)
    return (unsigned short)(u >> 16);
}
static __device__ __forceinline__ float bf2f(unsigned short h) {
    return __uint_as_float(((unsigned)h) << 16);
}

// Prep: zero loss; split codebook into bf16 hi/lo (coalesced); c2 per code.
__global__ __launch_bounds__(256) void vq_prep(
    const float* __restrict__ cb, float* __restrict__ out,
    unsigned short* __restrict__ cbh, unsigned short* __restrict__ cbl,
    float* __restrict__ c2)
{
    const int t  = threadIdx.x;
    const int k0 = blockIdx.x * 64;
    if (blockIdx.x == 0 && t == 0) out[OFF_LOSS] = 0.0f;

    const int d  = t & 63;
#pragma unroll
    for (int r = 0; r < 16; ++r) {
        const int k = k0 + r * 4 + (t >> 6);
        const float v = cb[(size_t)k * Dc + d];
        unsigned short h = f2bf(v);
        cbh[(size_t)k * Dc + d] = h;
        cbl[(size_t)k * Dc + d] = f2bf(v - bf2f(h));
    }
    if (t < 64) {
        const int k = k0 + t;
        const float* c = cb + (size_t)k * Dc;
        float s = 0.f;
#pragma unroll
        for (int dd = 0; dd < Dc; ++dd) s = __builtin_fmaf(c[dd], c[dd], s);
        c2[k] = s;
    }
}

// Codebook-stationary, occupancy-first: 16 waves x 64 codes in registers,
// X fragments in 32KB LDS, X re-read from global in recheck/epilogue.
// __launch_bounds__(1024, 4): 4 waves/EU -> VGPR cap 128 (r6 regression was
// the default cap of 64 forcing A-fragment spills to scratch).
__global__ __launch_bounds__(1024, 4) void vq_main(
    const float* __restrict__ in, const float* __restrict__ codebook,
    const unsigned short* __restrict__ cbh,
    const unsigned short* __restrict__ cbl,
    const float* __restrict__ c2g, float* __restrict__ out)
{
    __shared__ short8   xfh[1024];             // 16384 B
    __shared__ short8   xfl[1024];             // 16384 B
    __shared__ float    xpart[BLK_ROWS][8];    //  4096 B
    __shared__ float    xs2[BLK_ROWS];         //   512 B
    __shared__ float    cV1[WAVES][BLK_ROWS];  //  8192 B
    __shared__ float    cV2[WAVES][BLK_ROWS];  //  8192 B
    __shared__ unsigned cK [WAVES][BLK_ROWS];  //  8192 B
    __shared__ unsigned kpack[BLK_ROWS];       //   512 B   (total ~62.5 KB)

    const int tid  = threadIdx.x;
    const int lane = tid & 63;
    const int w    = __builtin_amdgcn_readfirstlane(tid >> 6);  // 0..15
    const int col  = lane & 15;
    const int g    = lane >> 4;

    const int bq = blockIdx.x >> 7;                    // batch (128 blk/batch)
    const int p0 = (blockIdx.x & 127) * BLK_ROWS;      // LHW offset
    const size_t inBase = (size_t)bq * (Cc * LHWc) + p0;

    // ---- this wave's 64 codes as A-fragments + biased c2 (registers) ----
    short8 Ah[4][2], Al[4][2];
    float  c2r[4][4];
#pragma unroll
    for (int ct = 0; ct < 4; ++ct) {
        const size_t cb0 = (size_t)(w * 64 + ct * 16 + col) * Dc + g * 8;
#pragma unroll
        for (int kt = 0; kt < 2; ++kt) {
            Ah[ct][kt] = *(const short8*)(cbh + cb0 + kt * 32);
            Al[ct][kt] = *(const short8*)(cbl + cb0 + kt * 32);
        }
#pragma unroll
        for (int r = 0; r < 4; ++r)
            c2r[ct][r] = c2g[w * 64 + ct * 16 + g * 4 + r] + 0.25f;
    }

    // ---- phase 1: build X fragments from global (1 hi+lo chunk/thread) ----
    {
        const int c  = tid;                    // chunk = t*128 + kt*64 + gi*16 + cl
        const int t  = c >> 7;
        const int kt = (c >> 6) & 1;
        const int gi = (c >> 4) & 3;
        const int cl = c & 15;
        const int row = t * 16 + cl;
        const float* xp = in + inBase + (size_t)(kt * 32 + gi * 8) * LHWc + row;
        float v[8];
#pragma unroll
        for (int j = 0; j < 8; ++j) v[j] = xp[(size_t)j * LHWc];
        float p = 0.f;
#pragma unroll
        for (int j = 0; j < 8; ++j) p = __builtin_fmaf(v[j], v[j], p);
        short8 h8, l8;
#pragma unroll
        for (int j = 0; j < 8; ++j) {
            unsigned short hv = f2bf(v[j]);
            h8[j] = (short)hv;
            l8[j] = (short)f2bf(v[j] - bf2f(hv));
        }
        xfh[c] = h8; xfl[c] = l8;
        xpart[row][kt * 4 + gi] = p;
    }
    __syncthreads();
    if (tid < BLK_ROWS) {
        const float* q = xpart[tid];
        xs2[tid] = ((q[0] + q[1]) + (q[2] + q[3])) + ((q[4] + q[5]) + (q[6] + q[7]));
    }

    // ---- main loop: 8 X-tiles, codes stay in registers ----
#pragma unroll 1
    for (int t = 0; t < 8; ++t) {
        const short8 xh0 = xfh[t * 128 + lane];
        const short8 xh1 = xfh[t * 128 + 64 + lane];
        const short8 xl0 = xfl[t * 128 + lane];
        const short8 xl1 = xfl[t * 128 + 64 + lane];

        float bV = 3.4e38f, sV = 3.4e38f;
        int   bK = 0, sK = 0;

#pragma unroll
        for (int ct = 0; ct < 4; ++ct) {
            f32x4 acc = {0.f, 0.f, 0.f, 0.f};
            // split-3 dot: hh + hl + lh (ll ~1e-8, covered by recheck)
            acc = __builtin_amdgcn_mfma_f32_16x16x32_bf16(Ah[ct][0], xh0, acc, 0, 0, 0);
            acc = __builtin_amdgcn_mfma_f32_16x16x32_bf16(Ah[ct][1], xh1, acc, 0, 0, 0);
            acc = __builtin_amdgcn_mfma_f32_16x16x32_bf16(Ah[ct][0], xl0, acc, 0, 0, 0);
            acc = __builtin_amdgcn_mfma_f32_16x16x32_bf16(Ah[ct][1], xl1, acc, 0, 0, 0);
            acc = __builtin_amdgcn_mfma_f32_16x16x32_bf16(Al[ct][0], xh0, acc, 0, 0, 0);
            acc = __builtin_amdgcn_mfma_f32_16x16x32_bf16(Al[ct][1], xh1, acc, 0, 0, 0);
#pragma unroll
            for (int r = 0; r < 4; ++r) {
                // argmin-equivalent score: c2[k]+0.25 - 2*dot (x2 folded out)
                float vv = __builtin_fmaf(-2.f, acc[r], c2r[ct][r]);
                const int k = w * 64 + ct * 16 + g * 4 + r;
                bool  c1 = vv < bV;
                float nb  = c1 ? vv : bV;
                int   nbk = c1 ? k : bK;
                float mx  = c1 ? bV : vv;
                int   mxk = c1 ? bK : k;
                bool  c2_ = mx < sV;
                sV = c2_ ? mx : sV;
                sK = c2_ ? mxk : sK;
                bV = nb; bK = nbk;
            }
        }

        // butterfly over g (lanes ^16, ^32): top-2 of wave's 64 codes per row
#pragma unroll
        for (int m = 16; m <= 32; m <<= 1) {
            float ob  = __shfl_xor(bV, m, 64);
            int   obk = __shfl_xor(bK, m, 64);
            float os  = __shfl_xor(sV, m, 64);
            int   osk = __shfl_xor(sK, m, 64);
            bool  c1 = ob < bV;
            float nb  = c1 ? ob : bV;
            int   nbk = c1 ? obk : bK;
            float mx  = c1 ? bV : ob;
            int   mxk = c1 ? bK : obk;
            bool  c3 = os < sV;
            float ms  = c3 ? os : sV;
            int   msk = c3 ? osk : sK;
            bool  c4 = mx < ms;
            sV = c4 ? mx : ms;
            sK = c4 ? mxk : msk;
            bV = nb; bK = nbk;
        }
        if (g == 0) {
            const int row = t * 16 + col;
            cV1[w][row] = bV;
            cV2[w][row] = sV;
            cK [w][row] = (unsigned)bK | ((unsigned)sK << 16);
        }
    }
    __syncthreads();

    // ---- merge 16 waves' top-2 per row (2 threads/row + pair shfl) ----
    if (tid < 2 * BLK_ROWS) {
        const int row = tid >> 1;
        const int h   = tid & 1;
        float b = 3.4e38f, s = 3.4e38f;
        int   bk = 0, sk = 0;
#pragma unroll
        for (int wv = 0; wv < 8; ++wv) {
            const int wj = h * 8 + wv;         // waves ascending => k ascending
            const unsigned ks = cK[wj][row];
            const float v1 = cV1[wj][row];
            const float v2 = cV2[wj][row];
            const int  k1 = (int)(ks & 0xFFFFu);
            const int  k2 = (int)(ks >> 16);
            {
                bool c1 = v1 < b;
                float mx = c1 ? b : v1;  int mxk = c1 ? bk : k1;
                b  = c1 ? v1 : b;        bk  = c1 ? k1 : bk;
                bool c2_ = mx < s;  s = c2_ ? mx : s;  sk = c2_ ? mxk : sk;
            }
            {
                bool c1 = v2 < b;
                float mx = c1 ? b : v2;  int mxk = c1 ? bk : k2;
                b  = c1 ? v2 : b;        bk  = c1 ? k2 : bk;
                bool c2_ = mx < s;  s = c2_ ? mx : s;  sk = c2_ ? mxk : sk;
            }
        }
        // combine halves (partner h=1 has strictly higher k's)
        float ob  = __shfl_xor(b, 1, 64);
        int   obk = __shfl_xor(bk, 1, 64);
        float os  = __shfl_xor(s, 1, 64);
        int   osk = __shfl_xor(sk, 1, 64);
        if (h == 0) {
            bool  c1 = ob < b;                 // tie keeps ours (lower k)
            float nb  = c1 ? ob : b;
            int   nbk = c1 ? obk : bk;
            float mx  = c1 ? b : ob;
            int   mxk = c1 ? bk : obk;
            bool  c3 = os < s;
            float ms  = c3 ? os : s;
            int   msk = c3 ? osk : sk;
            bool  c4 = mx < ms;
            int   fsk = c4 ? mxk : msk;
            kpack[row] = (unsigned)nbk | ((unsigned)fsk << 16);
        }
    }
    __syncthreads();

    // ---- exact recheck: 2 candidates/row, X re-read coalesced from global ----
    if (tid < 2 * BLK_ROWS) {
        const int row = tid >> 1;
        const int ci  = tid & 1;
        const unsigned pr = kpack[row];
        const int k = ci ? (int)(pr >> 16) : (int)(pr & 0xFFFFu);
        const float* cbr = codebook + (size_t)k * Dc;
        const float* xr  = in + inBase + row;
        float a0 = 0.f, a1 = 0.f, a2 = 0.f, a3 = 0.f;
#pragma unroll
        for (int d = 0; d < 64; d += 4) {
            a0 = __builtin_fmaf(xr[(size_t)(d + 0) * LHWc], cbr[d + 0], a0);
            a1 = __builtin_fmaf(xr[(size_t)(d + 1) * LHWc], cbr[d + 1], a1);
            a2 = __builtin_fmaf(xr[(size_t)(d + 2) * LHWc], cbr[d + 2], a2);
            a3 = __builtin_fmaf(xr[(size_t)(d + 3) * LHWc], cbr[d + 3], a3);
        }
        float a  = (a0 + a1) + (a2 + a3);
        float d2 = __builtin_fmaf(-2.f, a, xs2[row]) + c2g[k];
        unsigned long long pk =
            ((unsigned long long)__float_as_uint(d2) << 32) | (unsigned)k;
        unsigned long long o = __shfl_xor(pk, 1, 64);
        pk = o < pk ? o : pk;                  // min d2, ties -> lowest k
        if (ci == 0) {
            const int kwin = (int)(pk & 0x3FFu);
            kpack[row] = (unsigned)kwin;
            out[OFF_IDX + (size_t)blockIdx.x * BLK_ROWS + row] = (float)kwin;
        }
    }
    __syncthreads();

    // ---- quantized write + loss: 8 threads/row, 8 channels each ----
    {
        const int row = tid & 127;
        const int cp  = tid >> 7;              // 0..7 (wave-uniform pairs)
        const int kw  = (int)kpack[row];
        const float* cbw = codebook + (size_t)kw * Dc + cp * 8;
        const float* xr  = in + inBase + row;
        float* qout = out + inBase + row;
        float ls = 0.f;
#pragma unroll
        for (int j = 0; j < 8; ++j) {
            const int c = cp * 8 + j;
            float qv = cbw[j];
            qout[(size_t)c * LHWc] = qv;       // coalesced across lanes per c
            float e = qv - xr[(size_t)c * LHWc];
            ls = __builtin_fmaf(e, e, ls);
        }
#pragma unroll
        for (int off = 32; off > 0; off >>= 1) ls += __shfl_down(ls, off, 64);
        if (lane == 0) atomicAdd(&out[OFF_LOSS], ls * (1.25f / (float)QSIZE));
    }
}

extern "C" void kernel_launch(void* const* d_in, const int* in_sizes, int n_in,
                              void* d_out, int out_size, void* d_ws, size_t ws_size,
                              hipStream_t stream) {
    const float* in = (const float*)d_in[0];   // [4,64,16,32,32] f32
    const float* cb = (const float*)d_in[1];   // [1024,64] f32
    float* out = (float*)d_out;
    (void)in_sizes; (void)n_in; (void)out_size; (void)ws_size;

    unsigned short* cbh = (unsigned short*)d_ws;                 // 128 KB
    unsigned short* cbl = cbh + (size_t)Kc * Dc;                 // 128 KB
    float*          c2  = (float*)(cbl + (size_t)Kc * Dc);       // 4 KB

    vq_prep<<<dim3(16), dim3(256), 0, stream>>>(cb, out, cbh, cbl, c2);
    vq_main<<<dim3(Nc / BLK_ROWS), dim3(1024), 0, stream>>>(in, cb, cbh, cbl, c2, out);
}

// Round 8
// 201.850 us; speedup vs baseline: 1.0281x; 1.0281x over previous
//
#include <hip/hip_runtime.h>

// (B,C,L,H,W) = (4,64,16,32,32), K=1024, D=C=64
constexpr int Cc   = 64;
constexpr int Kc   = 1024;
constexpr int Dc   = 64;
constexpr int LHWc = 16 * 32 * 32;        // 16384
constexpr int Nc   = 4 * LHWc;            // 65536 vectors
constexpr int QSIZE    = 4 * Cc * LHWc;   // 4194304
constexpr int OFF_LOSS = QSIZE;           // 4194304
constexpr int OFF_IDX  = QSIZE + 1;       // 4194305

constexpr int BLK_ROWS = 128;             // rows per block
constexpr int WAVES    = 16;              // 1024 threads

typedef __attribute__((ext_vector_type(8))) short short8;   // 8 x bf16 bits
typedef __attribute__((ext_vector_type(4))) float f32x4;

static __device__ __forceinline__ unsigned short f2bf(float f) {
    unsigned u = __float_as_uint(f);
    u += 0x7FFFu + ((u >> 16) & 1u);      // RNE (finite data only)
    return (unsigned short)(u >> 16);
}
static __device__ __forceinline__ float bf2f(unsigned short h) {
    return __uint_as_float(((unsigned)h) << 16);
}

// Prep: zero loss; split codebook into bf16 hi/lo (coalesced); c2 per code.
__global__ __launch_bounds__(256) void vq_prep(
    const float* __restrict__ cb, float* __restrict__ out,
    unsigned short* __restrict__ cbh, unsigned short* __restrict__ cbl,
    float* __restrict__ c2)
{
    const int t  = threadIdx.x;
    const int k0 = blockIdx.x * 64;
    if (blockIdx.x == 0 && t == 0) out[OFF_LOSS] = 0.0f;

    const int d  = t & 63;
#pragma unroll
    for (int r = 0; r < 16; ++r) {
        const int k = k0 + r * 4 + (t >> 6);
        const float v = cb[(size_t)k * Dc + d];
        unsigned short h = f2bf(v);
        cbh[(size_t)k * Dc + d] = h;
        cbl[(size_t)k * Dc + d] = f2bf(v - bf2f(h));
    }
    if (t < 64) {
        const int k = k0 + t;
        const float* c = cb + (size_t)k * Dc;
        float s = 0.f;
#pragma unroll
        for (int dd = 0; dd < Dc; ++dd) s = __builtin_fmaf(c[dd], c[dd], s);
        c2[k] = s;
    }
}

// Codebook-stationary: 16 waves x 64 codes in registers, X frags in LDS.
// amdgpu_waves_per_eu(4,4): pin occupancy target to exactly 4 waves/EU so
// the register allocator uses the full 128-VGPR budget. r6/r7 showed that
// __launch_bounds__' min-waves arg only FLOORS occupancy; the heuristic
// still squeezed to 64 VGPR (8 waves/EU target) and spilled A-fragments
// to scratch (WRITE_SIZE 16.7 -> 25.1 MB). Setting max=4 removes the
// incentive to squeeze (LDS already caps us at 1 workgroup/CU).
__global__ __launch_bounds__(1024)
__attribute__((amdgpu_waves_per_eu(4, 4))) void vq_main(
    const float* __restrict__ in, const float* __restrict__ codebook,
    const unsigned short* __restrict__ cbh,
    const unsigned short* __restrict__ cbl,
    const float* __restrict__ c2g, float* __restrict__ out)
{
    __shared__ short8   xfh[1024];             // 16384 B
    __shared__ short8   xfl[1024];             // 16384 B
    __shared__ float    xpart[BLK_ROWS][8];    //  4096 B
    __shared__ float    xs2[BLK_ROWS];         //   512 B
    __shared__ float    cV1[WAVES][BLK_ROWS];  //  8192 B
    __shared__ float    cV2[WAVES][BLK_ROWS];  //  8192 B
    __shared__ unsigned cK [WAVES][BLK_ROWS];  //  8192 B
    __shared__ unsigned kpack[BLK_ROWS];       //   512 B   (total ~62.5 KB)

    const int tid  = threadIdx.x;
    const int lane = tid & 63;
    const int w    = __builtin_amdgcn_readfirstlane(tid >> 6);  // 0..15
    const int col  = lane & 15;
    const int g    = lane >> 4;

    const int bq = blockIdx.x >> 7;                    // batch (128 blk/batch)
    const int p0 = (blockIdx.x & 127) * BLK_ROWS;      // LHW offset
    const size_t inBase = (size_t)bq * (Cc * LHWc) + p0;

    // ---- this wave's 64 codes as A-fragments + biased c2 (registers) ----
    short8 Ah[4][2], Al[4][2];
    float  c2r[4][4];
#pragma unroll
    for (int ct = 0; ct < 4; ++ct) {
        const size_t cb0 = (size_t)(w * 64 + ct * 16 + col) * Dc + g * 8;
#pragma unroll
        for (int kt = 0; kt < 2; ++kt) {
            Ah[ct][kt] = *(const short8*)(cbh + cb0 + kt * 32);
            Al[ct][kt] = *(const short8*)(cbl + cb0 + kt * 32);
        }
#pragma unroll
        for (int r = 0; r < 4; ++r)
            c2r[ct][r] = c2g[w * 64 + ct * 16 + g * 4 + r] + 0.25f;
    }

    // ---- phase 1: build X fragments from global (1 hi+lo chunk/thread) ----
    {
        const int c  = tid;                    // chunk = t*128 + kt*64 + gi*16 + cl
        const int t  = c >> 7;
        const int kt = (c >> 6) & 1;
        const int gi = (c >> 4) & 3;
        const int cl = c & 15;
        const int row = t * 16 + cl;
        const float* xp = in + inBase + (size_t)(kt * 32 + gi * 8) * LHWc + row;
        float v[8];
#pragma unroll
        for (int j = 0; j < 8; ++j) v[j] = xp[(size_t)j * LHWc];
        float p = 0.f;
#pragma unroll
        for (int j = 0; j < 8; ++j) p = __builtin_fmaf(v[j], v[j], p);
        short8 h8, l8;
#pragma unroll
        for (int j = 0; j < 8; ++j) {
            unsigned short hv = f2bf(v[j]);
            h8[j] = (short)hv;
            l8[j] = (short)f2bf(v[j] - bf2f(hv));
        }
        xfh[c] = h8; xfl[c] = l8;
        xpart[row][kt * 4 + gi] = p;
    }
    __syncthreads();
    if (tid < BLK_ROWS) {
        const float* q = xpart[tid];
        xs2[tid] = ((q[0] + q[1]) + (q[2] + q[3])) + ((q[4] + q[5]) + (q[6] + q[7]));
    }

    // ---- main loop: 8 X-tiles, codes stay in registers ----
#pragma unroll 1
    for (int t = 0; t < 8; ++t) {
        const short8 xh0 = xfh[t * 128 + lane];
        const short8 xh1 = xfh[t * 128 + 64 + lane];
        const short8 xl0 = xfl[t * 128 + lane];
        const short8 xl1 = xfl[t * 128 + 64 + lane];

        float bV = 3.4e38f, sV = 3.4e38f;
        int   bK = 0, sK = 0;

#pragma unroll
        for (int ct = 0; ct < 4; ++ct) {
            f32x4 acc = {0.f, 0.f, 0.f, 0.f};
            // split-3 dot: hh + hl + lh (ll ~1e-8, covered by recheck)
            acc = __builtin_amdgcn_mfma_f32_16x16x32_bf16(Ah[ct][0], xh0, acc, 0, 0, 0);
            acc = __builtin_amdgcn_mfma_f32_16x16x32_bf16(Ah[ct][1], xh1, acc, 0, 0, 0);
            acc = __builtin_amdgcn_mfma_f32_16x16x32_bf16(Ah[ct][0], xl0, acc, 0, 0, 0);
            acc = __builtin_amdgcn_mfma_f32_16x16x32_bf16(Ah[ct][1], xl1, acc, 0, 0, 0);
            acc = __builtin_amdgcn_mfma_f32_16x16x32_bf16(Al[ct][0], xh0, acc, 0, 0, 0);
            acc = __builtin_amdgcn_mfma_f32_16x16x32_bf16(Al[ct][1], xh1, acc, 0, 0, 0);
#pragma unroll
            for (int r = 0; r < 4; ++r) {
                // argmin-equivalent score: c2[k]+0.25 - 2*dot (x2 folded out)
                float vv = __builtin_fmaf(-2.f, acc[r], c2r[ct][r]);
                const int k = w * 64 + ct * 16 + g * 4 + r;
                bool  c1 = vv < bV;
                float nb  = c1 ? vv : bV;
                int   nbk = c1 ? k : bK;
                float mx  = c1 ? bV : vv;
                int   mxk = c1 ? bK : k;
                bool  c2_ = mx < sV;
                sV = c2_ ? mx : sV;
                sK = c2_ ? mxk : sK;
                bV = nb; bK = nbk;
            }
        }

        // butterfly over g (lanes ^16, ^32): top-2 of wave's 64 codes per row
#pragma unroll
        for (int m = 16; m <= 32; m <<= 1) {
            float ob  = __shfl_xor(bV, m, 64);
            int   obk = __shfl_xor(bK, m, 64);
            float os  = __shfl_xor(sV, m, 64);
            int   osk = __shfl_xor(sK, m, 64);
            bool  c1 = ob < bV;
            float nb  = c1 ? ob : bV;
            int   nbk = c1 ? obk : bK;
            float mx  = c1 ? bV : ob;
            int   mxk = c1 ? bK : obk;
            bool  c3 = os < sV;
            float ms  = c3 ? os : sV;
            int   msk = c3 ? osk : sK;
            bool  c4 = mx < ms;
            sV = c4 ? mx : ms;
            sK = c4 ? mxk : msk;
            bV = nb; bK = nbk;
        }
        if (g == 0) {
            const int row = t * 16 + col;
            cV1[w][row] = bV;
            cV2[w][row] = sV;
            cK [w][row] = (unsigned)bK | ((unsigned)sK << 16);
        }
    }
    __syncthreads();

    // ---- merge 16 waves' top-2 per row (2 threads/row + pair shfl) ----
    if (tid < 2 * BLK_ROWS) {
        const int row = tid >> 1;
        const int h   = tid & 1;
        float b = 3.4e38f, s = 3.4e38f;
        int   bk = 0, sk = 0;
#pragma unroll
        for (int wv = 0; wv < 8; ++wv) {
            const int wj = h * 8 + wv;         // waves ascending => k ascending
            const unsigned ks = cK[wj][row];
            const float v1 = cV1[wj][row];
            const float v2 = cV2[wj][row];
            const int  k1 = (int)(ks & 0xFFFFu);
            const int  k2 = (int)(ks >> 16);
            {
                bool c1 = v1 < b;
                float mx = c1 ? b : v1;  int mxk = c1 ? bk : k1;
                b  = c1 ? v1 : b;        bk  = c1 ? k1 : bk;
                bool c2_ = mx < s;  s = c2_ ? mx : s;  sk = c2_ ? mxk : sk;
            }
            {
                bool c1 = v2 < b;
                float mx = c1 ? b : v2;  int mxk = c1 ? bk : k2;
                b  = c1 ? v2 : b;        bk  = c1 ? k2 : bk;
                bool c2_ = mx < s;  s = c2_ ? mx : s;  sk = c2_ ? mxk : sk;
            }
        }
        // combine halves (partner h=1 has strictly higher k's)
        float ob  = __shfl_xor(b, 1, 64);
        int   obk = __shfl_xor(bk, 1, 64);
        float os  = __shfl_xor(s, 1, 64);
        int   osk = __shfl_xor(sk, 1, 64);
        if (h == 0) {
            bool  c1 = ob < b;                 // tie keeps ours (lower k)
            float nb  = c1 ? ob : b;
            int   nbk = c1 ? obk : bk;
            float mx  = c1 ? b : ob;
            int   mxk = c1 ? bk : obk;
            bool  c3 = os < s;
            float ms  = c3 ? os : s;
            int   msk = c3 ? osk : sk;
            bool  c4 = mx < ms;
            int   fsk = c4 ? mxk : msk;
            kpack[row] = (unsigned)nbk | ((unsigned)fsk << 16);
        }
    }
    __syncthreads();

    // ---- exact recheck: 2 candidates/row, X re-read coalesced from global ----
    if (tid < 2 * BLK_ROWS) {
        const int row = tid >> 1;
        const int ci  = tid & 1;
        const unsigned pr = kpack[row];
        const int k = ci ? (int)(pr >> 16) : (int)(pr & 0xFFFFu);
        const float* cbr = codebook + (size_t)k * Dc;
        const float* xr  = in + inBase + row;
        float a0 = 0.f, a1 = 0.f, a2 = 0.f, a3 = 0.f;
#pragma unroll
        for (int d = 0; d < 64; d += 4) {
            a0 = __builtin_fmaf(xr[(size_t)(d + 0) * LHWc], cbr[d + 0], a0);
            a1 = __builtin_fmaf(xr[(size_t)(d + 1) * LHWc], cbr[d + 1], a1);
            a2 = __builtin_fmaf(xr[(size_t)(d + 2) * LHWc], cbr[d + 2], a2);
            a3 = __builtin_fmaf(xr[(size_t)(d + 3) * LHWc], cbr[d + 3], a3);
        }
        float a  = (a0 + a1) + (a2 + a3);
        float d2 = __builtin_fmaf(-2.f, a, xs2[row]) + c2g[k];
        unsigned long long pk =
            ((unsigned long long)__float_as_uint(d2) << 32) | (unsigned)k;
        unsigned long long o = __shfl_xor(pk, 1, 64);
        pk = o < pk ? o : pk;                  // min d2, ties -> lowest k
        if (ci == 0) {
            const int kwin = (int)(pk & 0x3FFu);
            kpack[row] = (unsigned)kwin;
            out[OFF_IDX + (size_t)blockIdx.x * BLK_ROWS + row] = (float)kwin;
        }
    }
    __syncthreads();

    // ---- quantized write + loss: 8 threads/row, 8 channels each ----
    {
        const int row = tid & 127;
        const int cp  = tid >> 7;              // 0..7 (wave-uniform pairs)
        const int kw  = (int)kpack[row];
        const float* cbw = codebook + (size_t)kw * Dc + cp * 8;
        const float* xr  = in + inBase + row;
        float* qout = out + inBase + row;
        float ls = 0.f;
#pragma unroll
        for (int j = 0; j < 8; ++j) {
            const int c = cp * 8 + j;
            float qv = cbw[j];
            qout[(size_t)c * LHWc] = qv;       // coalesced across lanes per c
            float e = qv - xr[(size_t)c * LHWc];
            ls = __builtin_fmaf(e, e, ls);
        }
#pragma unroll
        for (int off = 32; off > 0; off >>= 1) ls += __shfl_down(ls, off, 64);
        if (lane == 0) atomicAdd(&out[OFF_LOSS], ls * (1.25f / (float)QSIZE));
    }
}

extern "C" void kernel_launch(void* const* d_in, const int* in_sizes, int n_in,
                              void* d_out, int out_size, void* d_ws, size_t ws_size,
                              hipStream_t stream) {
    const float* in = (const float*)d_in[0];   // [4,64,16,32,32] f32
    const float* cb = (const float*)d_in[1];   // [1024,64] f32
    float* out = (float*)d_out;
    (void)in_sizes; (void)n_in; (void)out_size; (void)ws_size;

    unsigned short* cbh = (unsigned short*)d_ws;                 // 128 KB
    unsigned short* cbl = cbh + (size_t)Kc * Dc;                 // 128 KB
    float*          c2  = (float*)(cbl + (size_t)Kc * Dc);       // 4 KB

    vq_prep<<<dim3(16), dim3(256), 0, stream>>>(cb, out, cbh, cbl, c2);
    vq_main<<<dim3(Nc / BLK_ROWS), dim3(1024), 0, stream>>>(in, cb, cbh, cbl, c2, out);
}

// Round 9
// 159.763 us; speedup vs baseline: 1.2990x; 1.2634x over previous
//
#include <hip/hip_runtime.h>

// (B,C,L,H,W) = (4,64,16,32,32), K=1024, D=C=64
constexpr int Cc   = 64;
constexpr int Kc   = 1024;
constexpr int Dc   = 64;
constexpr int LHWc = 16 * 32 * 32;        // 16384
constexpr int Nc   = 4 * LHWc;            // 65536 vectors
constexpr int QSIZE    = 4 * Cc * LHWc;   // 4194304
constexpr int OFF_LOSS = QSIZE;           // 4194304
constexpr int OFF_IDX  = QSIZE + 1;       // 4194305

constexpr int BLK_ROWS = 128;             // rows per block
constexpr int NW       = 8;               // waves per block (512 threads)

typedef __attribute__((ext_vector_type(8))) short short8;   // 8 x bf16 bits
typedef __attribute__((ext_vector_type(4))) float f32x4;

static __device__ __forceinline__ unsigned short f2bf(float f) {
    unsigned u = __float_as_uint(f);
    u += 0x7FFFu + ((u >> 16) & 1u);      // RNE (finite data only)
    return (unsigned short)(u >> 16);
}
static __device__ __forceinline__ float bf2f(unsigned short h) {
    return __uint_as_float(((unsigned)h) << 16);
}

// Prep: zero loss; codebook bf16 hi/lo split; c2 (exact chain) and
// c2n = -0.5*(c2+0.25), the MFMA accumulator seed.
__global__ __launch_bounds__(256) void vq_prep(
    const float* __restrict__ cb, float* __restrict__ out,
    unsigned short* __restrict__ cbh, unsigned short* __restrict__ cbl,
    float* __restrict__ c2, float* __restrict__ c2n)
{
    const int t  = threadIdx.x;
    const int k0 = blockIdx.x * 64;
    if (blockIdx.x == 0 && t == 0) out[OFF_LOSS] = 0.0f;

    const int d  = t & 63;
#pragma unroll
    for (int r = 0; r < 16; ++r) {
        const int k = k0 + r * 4 + (t >> 6);
        const float v = cb[(size_t)k * Dc + d];
        unsigned short h = f2bf(v);
        cbh[(size_t)k * Dc + d] = h;
        cbl[(size_t)k * Dc + d] = f2bf(v - bf2f(h));
    }
    if (t < 64) {
        const int k = k0 + t;
        const float* c = cb + (size_t)k * Dc;
        float s = 0.f;
#pragma unroll
        for (int dd = 0; dd < Dc; ++dd) s = __builtin_fmaf(c[dd], c[dd], s);
        c2[k]  = s;
        c2n[k] = -0.5f * (s + 0.25f);     // acc seed: score = dot + c2n (maximize)
    }
}

// r5 structure (8 waves x 128 codes in registers, X frags in LDS) with the
// LDS diet: no f32 X tile, c2 seeded into the accumulator. 53 KB LDS ->
// 2 blocks/CU; (512,2) is the only declaration that produced no-spill
// codegen (r5: 120 VGPR). Occupancy comes from resources, not the bound.
__global__ __launch_bounds__(512, 2) void vq_main(
    const float* __restrict__ in, const float* __restrict__ codebook,
    const unsigned short* __restrict__ cbh,
    const unsigned short* __restrict__ cbl,
    const float* __restrict__ c2g, const float* __restrict__ c2ng,
    float* __restrict__ out)
{
    __shared__ short8   xfh[1024];             // 16384 B (8 tiles x 128 chunks)
    __shared__ short8   xfl[1024];             // 16384 B
    __shared__ float    c2ns[Kc];              //  4096 B
    __shared__ float    xpart[BLK_ROWS][8];    //  4096 B
    __shared__ float    xs2[BLK_ROWS];         //   512 B
    __shared__ float    cV1[NW][BLK_ROWS];     //  4096 B (bigger = better)
    __shared__ float    cV2[NW][BLK_ROWS];     //  4096 B
    __shared__ unsigned cK [NW][BLK_ROWS];     //  4096 B
    __shared__ unsigned kpack[BLK_ROWS];       //   512 B  (total 54272 B)

    const int tid  = threadIdx.x;
    const int lane = tid & 63;
    const int w    = __builtin_amdgcn_readfirstlane(tid >> 6);  // 0..7
    const int col  = lane & 15;
    const int g    = lane >> 4;

    const int bq = blockIdx.x >> 7;                    // batch (128 blk/batch)
    const int p0 = (blockIdx.x & 127) * BLK_ROWS;      // LHW offset
    const size_t inBase = (size_t)bq * (Cc * LHWc) + p0;

    // ---- stage c2n into LDS ----
    c2ns[tid]       = c2ng[tid];
    c2ns[tid + 512] = c2ng[tid + 512];

    // ---- phase 1: build X fragments from global (2 chunks/thread) ----
#pragma unroll
    for (int jj = 0; jj < 2; ++jj) {
        const int c  = tid + jj * 512;         // chunk = t*128 + kt*64 + gi*16 + cl
        const int t  = c >> 7;
        const int kt = (c >> 6) & 1;
        const int gi = (c >> 4) & 3;
        const int cl = c & 15;
        const int row = t * 16 + cl;
        const float* xp = in + inBase + (size_t)(kt * 32 + gi * 8) * LHWc + row;
        float v[8];
#pragma unroll
        for (int j = 0; j < 8; ++j) v[j] = xp[(size_t)j * LHWc];
        float p = 0.f;
#pragma unroll
        for (int j = 0; j < 8; ++j) p = __builtin_fmaf(v[j], v[j], p);
        short8 h8, l8;
#pragma unroll
        for (int j = 0; j < 8; ++j) {
            unsigned short hv = f2bf(v[j]);
            h8[j] = (short)hv;
            l8[j] = (short)f2bf(v[j] - bf2f(hv));
        }
        xfh[c] = h8; xfl[c] = l8;
        xpart[row][kt * 4 + gi] = p;
    }

    // ---- this wave's 128 codes as A-fragments (loaded ONCE) ----
    short8 Ah[8][2], Al[8][2];
#pragma unroll
    for (int ct = 0; ct < 8; ++ct) {
        const size_t cb0 = (size_t)(w * 128 + ct * 16 + col) * Dc + g * 8;
#pragma unroll
        for (int kt = 0; kt < 2; ++kt) {
            Ah[ct][kt] = *(const short8*)(cbh + cb0 + kt * 32);
            Al[ct][kt] = *(const short8*)(cbl + cb0 + kt * 32);
        }
    }
    __syncthreads();

    if (tid < BLK_ROWS) {
        const float* q = xpart[tid];
        xs2[tid] = ((q[0] + q[1]) + (q[2] + q[3])) + ((q[4] + q[5]) + (q[6] + q[7]));
    }

    // ---- main loop: 8 X-tiles, codes stay in registers ----
#pragma unroll 1
    for (int t = 0; t < 8; ++t) {
        const short8 xh0 = xfh[t * 128 + lane];
        const short8 xh1 = xfh[t * 128 + 64 + lane];
        const short8 xl0 = xfl[t * 128 + lane];
        const short8 xl1 = xfl[t * 128 + 64 + lane];

        float bV = -3.4e38f, sV = -3.4e38f;    // MAXIMIZE accf = dot + c2n
        int   bK = 0, sK = 0;

#pragma unroll
        for (int ct = 0; ct < 8; ++ct) {
            f32x4 acc = *(const f32x4*)&c2ns[w * 128 + ct * 16 + g * 4];
            // split-3 dot: hh + hl + lh (ll ~1e-8, covered by recheck)
            acc = __builtin_amdgcn_mfma_f32_16x16x32_bf16(Ah[ct][0], xh0, acc, 0, 0, 0);
            acc = __builtin_amdgcn_mfma_f32_16x16x32_bf16(Ah[ct][1], xh1, acc, 0, 0, 0);
            acc = __builtin_amdgcn_mfma_f32_16x16x32_bf16(Ah[ct][0], xl0, acc, 0, 0, 0);
            acc = __builtin_amdgcn_mfma_f32_16x16x32_bf16(Ah[ct][1], xl1, acc, 0, 0, 0);
            acc = __builtin_amdgcn_mfma_f32_16x16x32_bf16(Al[ct][0], xh0, acc, 0, 0, 0);
            acc = __builtin_amdgcn_mfma_f32_16x16x32_bf16(Al[ct][1], xh1, acc, 0, 0, 0);
#pragma unroll
            for (int r = 0; r < 4; ++r) {
                const float a = acc[r];
                const int   k = w * 128 + ct * 16 + g * 4 + r;
                bool  c1 = a > bV;
                float nb  = c1 ? a : bV;
                int   nbk = c1 ? k : bK;
                float mn  = c1 ? bV : a;
                int   mnk = c1 ? bK : k;
                bool  c2_ = mn > sV;
                sV = c2_ ? mn : sV;
                sK = c2_ ? mnk : sK;
                bV = nb; bK = nbk;
            }
        }

        // butterfly over g (lanes ^16, ^32): top-2 of wave's 128 codes per row
#pragma unroll
        for (int m = 16; m <= 32; m <<= 1) {
            float ob  = __shfl_xor(bV, m, 64);
            int   obk = __shfl_xor(bK, m, 64);
            float os  = __shfl_xor(sV, m, 64);
            int   osk = __shfl_xor(sK, m, 64);
            bool  c1 = ob > bV;
            float nb  = c1 ? ob : bV;
            int   nbk = c1 ? obk : bK;
            float mn  = c1 ? bV : ob;
            int   mnk = c1 ? bK : obk;
            bool  c3 = os > sV;
            float ms  = c3 ? os : sV;
            int   msk = c3 ? osk : sK;
            bool  c4 = mn > ms;
            sV = c4 ? mn : ms;
            sK = c4 ? mnk : msk;
            bV = nb; bK = nbk;
        }
        if (g == 0) {
            const int row = t * 16 + col;
            cV1[w][row] = bV;
            cV2[w][row] = sV;
            cK [w][row] = (unsigned)bK | ((unsigned)sK << 16);
        }
    }
    __syncthreads();

    // ---- merge 8 waves' top-2 per row (2 threads/row + pair shfl) ----
    if (tid < 2 * BLK_ROWS) {
        const int row = tid >> 1;
        const int h   = tid & 1;
        float b = -3.4e38f, s = -3.4e38f;
        int   bk = 0, sk = 0;
#pragma unroll
        for (int wv = 0; wv < 4; ++wv) {
            const int wj = h * 4 + wv;         // waves ascending => k ascending
            const unsigned ks = cK[wj][row];
            const float v1 = cV1[wj][row];
            const float v2 = cV2[wj][row];
            const int  k1 = (int)(ks & 0xFFFFu);
            const int  k2 = (int)(ks >> 16);
            {
                bool c1 = v1 > b;
                float mn = c1 ? b : v1;  int mnk = c1 ? bk : k1;
                b  = c1 ? v1 : b;        bk  = c1 ? k1 : bk;
                bool c2_ = mn > s;  s = c2_ ? mn : s;  sk = c2_ ? mnk : sk;
            }
            {
                bool c1 = v2 > b;
                float mn = c1 ? b : v2;  int mnk = c1 ? bk : k2;
                b  = c1 ? v2 : b;        bk  = c1 ? k2 : bk;
                bool c2_ = mn > s;  s = c2_ ? mn : s;  sk = c2_ ? mnk : sk;
            }
        }
        // combine halves (partner h=1 has strictly higher k's)
        float ob  = __shfl_xor(b, 1, 64);
        int   obk = __shfl_xor(bk, 1, 64);
        float os  = __shfl_xor(s, 1, 64);
        int   osk = __shfl_xor(sk, 1, 64);
        if (h == 0) {
            bool  c1 = ob > b;                 // tie keeps ours (lower k)
            float nb  = c1 ? ob : b;
            int   nbk = c1 ? obk : bk;
            float mn  = c1 ? b : ob;
            int   mnk = c1 ? bk : obk;
            bool  c3 = os > s;
            float ms  = c3 ? os : s;
            int   msk = c3 ? osk : sk;
            bool  c4 = mn > ms;
            int   fsk = c4 ? mnk : msk;
            kpack[row] = (unsigned)nbk | ((unsigned)fsk << 16);
        }
    }
    __syncthreads();

    // ---- exact recheck: 2 candidates/row, X re-read coalesced from global ----
    if (tid < 2 * BLK_ROWS) {
        const int row = tid >> 1;
        const int ci  = tid & 1;
        const unsigned pr = kpack[row];
        const int k = ci ? (int)(pr >> 16) : (int)(pr & 0xFFFFu);
        const float* cbr = codebook + (size_t)k * Dc;
        const float* xr  = in + inBase + row;
        float a0 = 0.f, a1 = 0.f, a2 = 0.f, a3 = 0.f;
#pragma unroll
        for (int d = 0; d < 64; d += 4) {
            a0 = __builtin_fmaf(xr[(size_t)(d + 0) * LHWc], cbr[d + 0], a0);
            a1 = __builtin_fmaf(xr[(size_t)(d + 1) * LHWc], cbr[d + 1], a1);
            a2 = __builtin_fmaf(xr[(size_t)(d + 2) * LHWc], cbr[d + 2], a2);
            a3 = __builtin_fmaf(xr[(size_t)(d + 3) * LHWc], cbr[d + 3], a3);
        }
        float a  = (a0 + a1) + (a2 + a3);
        float d2 = __builtin_fmaf(-2.f, a, xs2[row]) + c2g[k];
        unsigned long long pk =
            ((unsigned long long)__float_as_uint(d2) << 32) | (unsigned)k;
        unsigned long long o = __shfl_xor(pk, 1, 64);
        pk = o < pk ? o : pk;                  // min d2, ties -> lowest k
        if (ci == 0) {
            const int kwin = (int)(pk & 0x3FFu);
            kpack[row] = (unsigned)kwin;
            out[OFF_IDX + (size_t)blockIdx.x * BLK_ROWS + row] = (float)kwin;
        }
    }
    __syncthreads();

    // ---- quantized write + loss: 4 threads/row, 16 channels each ----
    {
        const int row = tid & 127;
        const int cp  = tid >> 7;              // 0..3
        const int kw  = (int)kpack[row];
        const float* cbw = codebook + (size_t)kw * Dc + cp * 16;
        const float* xr  = in + inBase + row;
        float* qout = out + inBase + row;
        float ls = 0.f;
#pragma unroll
        for (int j = 0; j < 16; ++j) {
            const int c = cp * 16 + j;
            float qv = cbw[j];
            qout[(size_t)c * LHWc] = qv;       // coalesced across lanes per c
            float e = qv - xr[(size_t)c * LHWc];
            ls = __builtin_fmaf(e, e, ls);
        }
#pragma unroll
        for (int off = 32; off > 0; off >>= 1) ls += __shfl_down(ls, off, 64);
        if (lane == 0) atomicAdd(&out[OFF_LOSS], ls * (1.25f / (float)QSIZE));
    }
}

extern "C" void kernel_launch(void* const* d_in, const int* in_sizes, int n_in,
                              void* d_out, int out_size, void* d_ws, size_t ws_size,
                              hipStream_t stream) {
    const float* in = (const float*)d_in[0];   // [4,64,16,32,32] f32
    const float* cb = (const float*)d_in[1];   // [1024,64] f32
    float* out = (float*)d_out;
    (void)in_sizes; (void)n_in; (void)out_size; (void)ws_size;

    unsigned short* cbh = (unsigned short*)d_ws;                 // 128 KB
    unsigned short* cbl = cbh + (size_t)Kc * Dc;                 // 128 KB
    float*          c2  = (float*)(cbl + (size_t)Kc * Dc);       // 4 KB
    float*          c2n = c2 + Kc;                               // 4 KB

    vq_prep<<<dim3(16), dim3(256), 0, stream>>>(cb, out, cbh, cbl, c2, c2n);
    vq_main<<<dim3(Nc / BLK_ROWS), dim3(512), 0, stream>>>(in, cb, cbh, cbl, c2, c2n, out);
}